// Round 9
// baseline (235.443 us; speedup 1.0000x reference)
//
#include <hip/hip_runtime.h>
#include <math.h>

typedef _Float16 Hh;
typedef __attribute__((ext_vector_type(8))) _Float16 half8;
typedef __attribute__((ext_vector_type(4))) _Float16 half4;
typedef __attribute__((ext_vector_type(4))) float float4v;

#define B_ 2
#define H_ 16
#define N_ 2048
#define D_ 64
#define ND_ (N_*D_)
#define C1 0.04508422f   // (1/32)*log2(e); softmax in base-2 throughout

// Barrier WITHOUT the vmcnt(0) drain __syncthreads would emit.
#define BAR() asm volatile("s_waitcnt lgkmcnt(0)\n\ts_barrier" ::: "memory")

// attend LDS layouts (i-tile 32), conflict-free strides:
// Ebuf: [j(32)][i(32)][f(16+4pad)]  j-stride 644 halves, i-stride 20
#define EB_JS 644
#define EB_IS 20
// Pm: [e(16)][i(32)][j(32+4pad)]    e-stride 1156 halves, i-stride 36
#define PM_ES 1156
#define PM_IS 36

// ---------------------------------------------------------------------------
// K1: prep. (unchanged R6/R7/R8 version, no launch_bounds)
// ---------------------------------------------------------------------------
__global__ void prep_kernel(const float* __restrict__ q,
    const float* __restrict__ k, const float* __restrict__ v,
    const float* __restrict__ Wpre,
    Hh* __restrict__ qb, Hh* __restrict__ kb, Hh* __restrict__ vt2,
    float4* __restrict__ out4, float4* __restrict__ lacc4)
{
    int tid = threadIdx.x;
    int bid = blockIdx.x;
    if (bid < 512) {
        __shared__ float wsh[256];
        wsh[tid] = Wpre[tid];
        __syncthreads();
        int tensor = bid >> 8;
        int g = ((bid & 255) << 8) | tid;     // 0 .. 65535
        int b = g >> 15;
        int r = g & 32767;                    // (n,d4): n*16 + d4
        const float4* src = (const float4*)(tensor ? k : q);
        Hh* dst = tensor ? kb : qb;
        float4 x[16];
        #pragma unroll
        for (int f=0; f<16; f++) x[f] = src[(size_t)(b*16+f)*32768 + r];
        #pragma unroll
        for (int e=0; e<16; e++) {
            float4 a = make_float4(0.f,0.f,0.f,0.f);
            #pragma unroll
            for (int f=0; f<16; f++) {
                float wv = wsh[e*16+f];
                a.x += wv*x[f].x; a.y += wv*x[f].y; a.z += wv*x[f].z; a.w += wv*x[f].w;
            }
            half4 hv; hv[0]=(Hh)a.x; hv[1]=(Hh)a.y; hv[2]=(Hh)a.z; hv[3]=(Hh)a.w;
            *(half4*)(dst + (size_t)(b*16+e)*ND_ + (size_t)r*4) = hv;
        }
    } else if (bid < 768) {
        __shared__ Hh tile[64*48];            // [d][j], stride 48 halves
        int tb = bid - 512;                   // 0..255
        int be = tb >> 3;                     // 0..31
        int jtg = tb & 7;
        const float4* v4 = (const float4*)v;
        for (int u=0; u<8; u++) {
            int jt = jtg*8 + u;               // 0..63
            #pragma unroll
            for (int p=0; p<2; p++) {
                int j = p*16 + (tid>>4);
                int d4 = tid & 15;
                float4 val = v4[(size_t)be*32768 + (size_t)(jt*32+j)*16 + d4];
                tile[(d4*4+0)*48 + j] = (Hh)val.x;
                tile[(d4*4+1)*48 + j] = (Hh)val.y;
                tile[(d4*4+2)*48 + j] = (Hh)val.z;
                tile[(d4*4+3)*48 + j] = (Hh)val.w;
            }
            BAR();
            {
                int d = tid >> 2;
                int jc = (tid & 3) * 8;
                half8 o;
                #pragma unroll
                for (int z=0; z<8; z++) o[z] = tile[d*48 + jc + z];
                *(half8*)(vt2 + ((size_t)(be*64) + jt)*2048 + (size_t)tid*8) = o;
            }
            BAR();
        }
    } else {
        // zero out + lacc. out = 2*16*2048*64 floats = 1048576 float4.
        int zid = (bid - 768) * 256 + tid;    // 0 .. 262143
        float4 zz = make_float4(0.f,0.f,0.f,0.f);
        #pragma unroll
        for (int u=0; u<4; u++) out4[(size_t)u*262144 + zid] = zz;
        if (zid < 16384) lacc4[zid] = zz;
    }
}

// ---------------------------------------------------------------------------
// K2: denominators — R8 body; launch_bounds (1024,2). Empirical hipcc rule
// across R0-R8: granted VGPR = 512/(2*min_waves_per_eu). Declaring 2 yields
// a 128-VGPR budget (hard-capped at 128 by the 16-wave-block launch
// constraint), so the ~75-90-reg live set stops spilling.
// ---------------------------------------------------------------------------
__global__ __launch_bounds__(1024,2)
void denom_kernel(const Hh* __restrict__ qb,
    const Hh* __restrict__ kb, float* __restrict__ lacc_g)
{
    int bid = blockIdx.x;                 // 0..255
    int s = bid & 7;                      // j-slab, XCD-aligned
    int idx = bid >> 3;                   // 0..31
    int b = idx & 1;
    int pr = idx >> 1;                    // 0..15: triangle pair id
    int tid = threadIdx.x;
    int lane = tid & 63, w = tid >> 6;    // w = head f, 0..15
    int qd = lane >> 4, c = lane & 15;

    const Hh* qh = qb + (size_t)(b*16 + w)*ND_;
    const Hh* kh = kb + (size_t)(b*16 + w)*ND_;

    for (int hf = 0; hf < 2; hf++) {
        int it = hf ? (31 - pr) : pr;     // 64-row i-tile index
        int i0 = it * 64;

        half8 aq[4][2];
        #pragma unroll
        for (int ig=0; ig<4; ig++) {
            const Hh* qr = qh + (size_t)(i0 + ig*16 + c)*64 + qd*8;
            aq[ig][0] = *(const half8*)qr;
            aq[ig][1] = *(const half8*)(qr+32);
        }
        float lacc[4][4];
        #pragma unroll
        for (int ig=0; ig<4; ig++)
            #pragma unroll
            for (int r=0; r<4; r++) lacc[ig][r] = 0.f;

        int jtmax = 2*it + 1;             // last 32-j tile touching row i0+63
        for (int jt = s; jt <= jtmax; jt += 8) {
            int j0 = jt*32;
            #pragma unroll
            for (int jh=0; jh<2; jh++) {
                const Hh* kr = kh + (size_t)(j0 + jh*16 + c)*64 + qd*8;
                half8 b0 = *(const half8*)kr;
                half8 b1 = *(const half8*)(kr+32);
                int j = j0 + jh*16 + c;
                #pragma unroll
                for (int ig=0; ig<4; ig++) {
                    float4v sv = {0.f,0.f,0.f,0.f};
                    sv = __builtin_amdgcn_mfma_f32_16x16x32_f16(aq[ig][0], b0, sv, 0,0,0);
                    sv = __builtin_amdgcn_mfma_f32_16x16x32_f16(aq[ig][1], b1, sv, 0,0,0);
                    #pragma unroll
                    for (int r=0; r<4; r++) {
                        int i = i0 + ig*16 + qd*4 + r;
                        float ev = (j <= i) ? __builtin_amdgcn_exp2f(sv[r]*C1) : 0.f;
                        lacc[ig][r] += ev;
                    }
                }
            }
        }
        #pragma unroll
        for (int ig=0; ig<4; ig++) {
            #pragma unroll
            for (int r=0; r<4; r++) {
                float vs = lacc[ig][r];
                vs += __shfl_xor(vs, 1);
                vs += __shfl_xor(vs, 2);
                vs += __shfl_xor(vs, 4);
                vs += __shfl_xor(vs, 8);
                if (c == 0)
                    unsafeAtomicAdd(&lacc_g[(size_t)(b*16+w)*N_ + i0 + ig*16 + qd*4 + r], vs);
            }
        }
    }
}

// ---------------------------------------------------------------------------
// K3: main fused pass — R8 body VERBATIM; launch_bounds (1024,2).
// Empirical allocation rule (8 rounds of evidence): granted VGPR =
// 512/(2*min_declared). (1024,4)->64 starved the R7 prefetch into scratch
// (FETCH +20 MB, WRITE +37 MB of spill traffic). (1024,2) -> 128 budget;
// live set ~115 -> kn/vn genuinely stay in flight across mix+BAR+PV.
// The 16-wave block still launches (cap 128 ensures 4 waves/EU).
// ---------------------------------------------------------------------------
__global__ __launch_bounds__(1024,2)
void attend_kernel(const Hh* __restrict__ qb,
    const Hh* __restrict__ kb, const Hh* __restrict__ vt2,
    const float* __restrict__ lacc_g, const float* __restrict__ Wpost,
    float* __restrict__ out)
{
    __shared__ Hh Ebuf[32*EB_JS];   // 41216 B
    __shared__ Hh Pm[16*PM_ES];     // 36992 B

    int bid = blockIdx.x;                      // 0..255
    int s = (bid & 7) >> 1;                    // slab 0..3, XCD-pair aligned
    int b = bid & 1;
    int pr = bid >> 3;                         // 0..31: triangle pair id

    int tid = threadIdx.x;
    int lane = tid & 63, w = tid >> 6;         // w 0..15
    int qd = lane >> 4, c = lane & 15;

    // ---- mix role constants
    int jh2 = w & 1, ib = 4*(w >> 1);
    half4 wf;   // B[k=f=qd*4+z][n=e=c] = Wpost[e][f]
    #pragma unroll
    for (int z=0; z<4; z++) wf[z] = (Hh)Wpost[c*16 + qd*4 + z];

    for (int hf = 0; hf < 2; hf++) {
        int it = hf ? (63 - pr) : pr;          // 32-row i-tile index
        if (s > it) continue;                  // uniform per block
        int i0 = it * 32;

        // ---- scores state: head f = w, both ig
        half8 aq[2][2];
        float lgr[2][4];
        #pragma unroll
        for (int ig=0; ig<2; ig++) {
            const Hh* qr = qb + (size_t)((b*16+w)*N_ + i0 + ig*16 + c)*64 + qd*8;
            aq[ig][0] = *(const half8*)qr;
            aq[ig][1] = *(const half8*)(qr+32);
            #pragma unroll
            for (int r=0; r<4; r++)
                lgr[ig][r] = __builtin_amdgcn_logf(
                    lacc_g[(size_t)(b*16+w)*N_ + i0 + ig*16 + qd*4 + r]);
        }

        float4v acc[2][4];
        #pragma unroll
        for (int ig=0; ig<2; ig++) for (int nc=0; nc<4; nc++)
            acc[ig][nc] = (float4v){0.f,0.f,0.f,0.f};

        auto loadK = [&](int jt, half8 (&kk)[2][2]) {
            #pragma unroll
            for (int jh=0; jh<2; jh++) {
                const Hh* kr = kb + (size_t)((b*16+w)*N_ + jt*32 + jh*16 + c)*64 + qd*8;
                kk[jh][0] = *(const half8*)kr;
                kk[jh][1] = *(const half8*)(kr+32);
            }
        };
        auto loadV = [&](int jt, half8 (&vv)[4]) {
            #pragma unroll
            for (int nc=0; nc<4; nc++)
                vv[nc] = *(const half8*)(vt2 +
                    (size_t)((b*16+w)*64 + jt)*2048 + (nc*16+c)*32 + qd*8);
        };

        auto scores = [&](int jt, half8 (&kk)[2][2]) {
            #pragma unroll
            for (int jh=0; jh<2; jh++) {
                int j = jt*32 + jh*16 + c;
                #pragma unroll
                for (int ig=0; ig<2; ig++) {
                    float4v sv = {0.f,0.f,0.f,0.f};
                    sv = __builtin_amdgcn_mfma_f32_16x16x32_f16(aq[ig][0], kk[jh][0], sv, 0,0,0);
                    sv = __builtin_amdgcn_mfma_f32_16x16x32_f16(aq[ig][1], kk[jh][1], sv, 0,0,0);
                    #pragma unroll
                    for (int r=0; r<4; r++) {
                        int i = i0 + ig*16 + qd*4 + r;
                        float ev = (j <= i) ?
                            __builtin_amdgcn_exp2f(sv[r]*C1 - lgr[ig][r]) : 0.f;
                        Ebuf[(size_t)(jh*16+c)*EB_JS + (ig*16+qd*4+r)*EB_IS + w] = (Hh)ev;
                    }
                }
            }
        };

        half8 kk[2][2], vv[4];
        loadK(s, kk);
        loadV(s, vv);
        scores(s, kk);
        BAR();

        for (int jt = s; jt <= it; jt += 4) {
            bool more = (jt + 4 <= it);
            // ---- prefetch next tile's K and V into registers ----
            half8 kn[2][2], vn[4];
            if (more) { loadK(jt + 4, kn); loadV(jt + 4, vn); }
            // ---- head mix: Pm[e,i,j] for this wave's (jh2, i-quad) ----
            #pragma unroll
            for (int ii=0; ii<4; ii++) {
                int i = ib + ii;
                half4 ef = *(const half4*)&Ebuf[(jh2*16+c)*EB_JS + i*EB_IS + qd*4];
                float4v cc = {0.f,0.f,0.f,0.f};
                cc = __builtin_amdgcn_mfma_f32_16x16x16f16(ef, wf, cc, 0,0,0);
                half4 hv;
                #pragma unroll
                for (int r=0; r<4; r++) hv[r] = (Hh)cc[r];
                *(half4*)&Pm[c*PM_ES + i*PM_IS + jh2*16 + qd*4] = hv;
            }
            BAR();
            // ---- PV(jt): head e=w, both ig (V already in regs) ----
            #pragma unroll
            for (int nc=0; nc<4; nc++) {
                #pragma unroll
                for (int ig=0; ig<2; ig++) {
                    half8 pa = *(const half8*)&Pm[w*PM_ES + (ig*16+c)*PM_IS + qd*8];
                    acc[ig][nc] = __builtin_amdgcn_mfma_f32_16x16x32_f16(pa, vv[nc], acc[ig][nc], 0,0,0);
                }
            }
            // ---- scores(jt+4) with prefetched K ----
            if (more) {
                scores(jt + 4, kn);
                #pragma unroll
                for (int nc=0; nc<4; nc++) vv[nc] = vn[nc];
            }
            BAR();
        }

        // ---- accumulate partial O (nc order rotated by slab) ----
        #pragma unroll
        for (int ig=0; ig<2; ig++) {
            #pragma unroll
            for (int nc0=0; nc0<4; nc0++) {
                int nc = (nc0 + s) & 3;
                #pragma unroll
                for (int r=0; r<4; r++)
                    unsafeAtomicAdd(&out[(size_t)((b*16+w)*N_ + i0 + ig*16 + qd*4 + r)*64 + nc*16 + c],
                                    acc[ig][nc][r]);
            }
        }
    }
}

extern "C" void kernel_launch(void* const* d_in, const int* in_sizes, int n_in,
                              void* d_out, int out_size, void* d_ws, size_t ws_size,
                              hipStream_t stream) {
    const float* q     = (const float*)d_in[0];
    const float* k     = (const float*)d_in[1];
    const float* v     = (const float*)d_in[2];
    const float* Wpre  = (const float*)d_in[3];
    const float* Wpost = (const float*)d_in[4];
    float* out = (float*)d_out;

    size_t tsz = (size_t)B_*H_*N_*D_;       // 4 Mi halves = 8 MB each
    Hh* qb = (Hh*)d_ws;
    Hh* kb = qb + tsz;
    Hh* vt2 = kb + tsz;
    float* lacc = (float*)(vt2 + tsz);      // 24 MB offset, 256 KB

    prep_kernel<<<1792, 256, 0, stream>>>(q, k, v, Wpre, qb, kb, vt2,
                                          (float4*)out, (float4*)lacc);
    denom_kernel<<<256, 1024, 0, stream>>>(qb, kb, lacc);
    attend_kernel<<<256, 1024, 0, stream>>>(qb, kb, vt2, lacc, Wpost, out);
}